// Round 7
// baseline (215.956 us; speedup 1.0000x reference)
//
#include <hip/hip_runtime.h>
#include <hip/hip_bf16.h>
#include <stdint.h>

// VectorQuantizer on MI355X (gfx950) — round 7
// inputs: x [64,256,32,32] fp32 (NCHW), codebook [1024,256] fp32
// outputs: q_st [64,256,32,32] fp32 (codebook[argmin] scattered back), loss scalar
//
// Flipped GEMM D[m=code][n=hw] via mfma_f32_32x32x16_bf16; x staged once to
// LDS in B-frag order (R5); A-stream batch-prefetched per m-tile (R6).
// R7: wave re-tiled 32x512 -> 64x256 (2 n-tiles x 8 m-tiles, dual acc).
// Each A-frag feeds 2 MFMAs -> codebook L2 traffic 1.07 GB -> 537 MB and
// per-MFMA A-latency pressure halves. Wave count/occupancy unchanged.

#define DIM 256

typedef __attribute__((ext_vector_type(8)))  short bf16x8_t;   // MFMA A/B frag (4 VGPRs)
typedef __attribute__((ext_vector_type(4)))  float f32x4_t;
typedef __attribute__((ext_vector_type(16))) float f32x16_t;   // 32x32 C/D frag

__device__ __forceinline__ uint32_t f2bf(float f) {
    union { float f; uint32_t u; } v; v.f = f;
    uint32_t r = v.u + 0x7FFFu + ((v.u >> 16) & 1u);   // RNE
    return r >> 16;
}

// ---- prep: one wave per code. Emits (a) bf16 codebook in exact MFMA A-frag
// order: entry e=(mt*16+ks)*64+lane2 holds cb[mt*32+(lane2&31)][ks*16+(lane2>>5)*8+j],
// and (b) -0.5*||c||^2 in C/D-register order (nh_ord[mt*32 + half*16 + r]).
__global__ __launch_bounds__(256) void vq_prep(const float* __restrict__ cb,
                                               char* __restrict__ cbsw,
                                               float* __restrict__ nh_ord) {
    const int code = blockIdx.x * 4 + (threadIdx.x >> 6);
    const int l    = threadIdx.x & 63;               // holds d = 4l..4l+3
    const f32x4_t v = ((const f32x4_t*)(cb + code * DIM))[l];
    float sq = v.x * v.x + v.y * v.y + v.z * v.z + v.w * v.w;

    const int mt = code >> 5;
    const int ks = l >> 2;               // d/16
    const int hl = (l >> 1) & 1;         // (d%16)/8
    const uint32_t ebyte = (uint32_t)(((mt * 16 + ks) * 64 + (code & 31) + 32 * hl) * 16
                                      + (l & 1) * 8);
    uint2 o;
    o.x = f2bf(v.x) | (f2bf(v.y) << 16);
    o.y = f2bf(v.z) | (f2bf(v.w) << 16);
    *(uint2*)(cbsw + ebyte) = o;

    #pragma unroll
    for (int m = 32; m; m >>= 1) sq += __shfl_xor(sq, m);
    if (l == 0) {
        const int rw = code & 31;
        const int h4 = (rw >> 2) & 1;
        const int r  = (rw & 3) | ((rw >> 3) << 2);
        nh_ord[mt * 32 + h4 * 16 + r] = -0.5f * sq;
    }
}

// ---- main: 1024 blocks x 256 threads; block = 64 hw rows x all 1024 codes.
// LDS xt entry E=(ks*2+half)*64+row holds x[row][ks*16+half*8 .. +7] as 8 bf16.
// Wave w = code quarter (codes w*256..): both n-tiles (rows 0-31 / 32-63).
__global__ __launch_bounds__(256, 3) void vq_main(const float* __restrict__ x,
                                                  const float* __restrict__ cb,
                                                  const bf16x8_t* __restrict__ cbsw,
                                                  const float* __restrict__ nh_ord,
                                                  float* __restrict__ out,
                                                  float* __restrict__ loss_accum) {
    __shared__ uint32_t xt[16 * 2 * 64 * 4];   // 32 KB, B-frag order
    __shared__ float smin[4][64];
    __shared__ int   sidx[4][64];
    __shared__ float sxsq[4];
    __shared__ int   sfin[64];

    const int t     = threadIdx.x;
    const int w     = t >> 6;         // code quarter
    const int lane  = t & 63;
    const int n0    = blockIdx.x * 64;
    const int batch = n0 >> 10;
    const int hw0   = n0 & 1023;

    // ---- stage x -> LDS in fragment order (conflict-free b128 writes) + ||x||^2
    {
        const int col = t & 63;          // hw row within block
        const int oct = t >> 6;          // 0..3: d-octet selector
        const float* xp = x + (size_t)batch * (DIM * 1024) + hw0 + col;
        float sq = 0.f;
        #pragma unroll
        for (int i = 0; i < 8; ++i) {
            const int d0 = oct * 8 + i * 32;     // 8 consecutive d, one LDS entry
            float a[8];
            #pragma unroll
            for (int j = 0; j < 8; ++j) {
                a[j] = xp[(size_t)(d0 + j) * 1024];
                sq += a[j] * a[j];
            }
            uint4 pk;
            pk.x = f2bf(a[0]) | (f2bf(a[1]) << 16);
            pk.y = f2bf(a[2]) | (f2bf(a[3]) << 16);
            pk.z = f2bf(a[4]) | (f2bf(a[5]) << 16);
            pk.w = f2bf(a[6]) | (f2bf(a[7]) << 16);
            const int ks   = d0 >> 4;
            const int half = (d0 >> 3) & 1;
            *(uint4*)&xt[(ks * 512) + (half * 256) + col * 4] = pk;
        }
        #pragma unroll
        for (int m = 32; m; m >>= 1) sq += __shfl_xor(sq, m);
        if (lane == 0) sxsq[w] = sq;
    }
    __syncthreads();

    // ---- K-loop: wave's 256 codes (8 m-tiles) x both n-tiles; argmax(dot-0.5||c||^2)
    const int half = lane >> 5;
    const int col  = lane & 31;
    const uint32_t* xb0 = xt + half * 256 + col * 4;          // rows 0..31
    const uint32_t* xb1 = xb0 + 32 * 4;                        // rows 32..63

    float best0 = -3.0e38f, best1 = -3.0e38f;
    int   bi0 = 0, bi1 = 0;
    for (int i = 0; i < 8; ++i) {
        const int mt = w * 8 + i;

        // batch-prefetch all 16 A-frags of this m-tile
        bf16x8_t apre[16];
        {
            const bf16x8_t* ap = cbsw + mt * (16 * 64) + lane;
            #pragma unroll
            for (int ks = 0; ks < 16; ++ks) apre[ks] = ap[ks * 64];
        }

        const f32x4_t* nhp = (const f32x4_t*)(nh_ord + mt * 32 + half * 16);
        const f32x4_t h0 = nhp[0], h1 = nhp[1], h2 = nhp[2], h3 = nhp[3];
        f32x16_t acc0, acc1;
        #pragma unroll
        for (int r = 0; r < 4; ++r) {
            acc0[r] = h0[r]; acc0[4 + r] = h1[r]; acc0[8 + r] = h2[r]; acc0[12 + r] = h3[r];
        }
        acc1 = acc0;
        #pragma unroll
        for (int ks = 0; ks < 16; ++ks) {
            const bf16x8_t b0 = *(const bf16x8_t*)(xb0 + ks * 512);
            const bf16x8_t b1 = *(const bf16x8_t*)(xb1 + ks * 512);
            acc0 = __builtin_amdgcn_mfma_f32_32x32x16_bf16(apre[ks], b0, acc0, 0, 0, 0);
            acc1 = __builtin_amdgcn_mfma_f32_32x32x16_bf16(apre[ks], b1, acc1, 0, 0, 0);
        }
        #pragma unroll
        for (int r = 0; r < 16; ++r) {
            const int code = mt * 32 + half * 4 + ((r & 3) + 8 * (r >> 2));
            if (acc0[r] > best0) { best0 = acc0[r]; bi0 = code; }
            if (acc1[r] > best1) { best1 = acc1[r]; bi1 = code; }
        }
    }

    // ---- combine the two k-half lanes (same hw row, disjoint code subsets)
    {
        float ov = __shfl_xor(best0, 32); int oi = __shfl_xor(bi0, 32);
        if (ov > best0 || (ov == best0 && oi < bi0)) { best0 = ov; bi0 = oi; }
        ov = __shfl_xor(best1, 32); oi = __shfl_xor(bi1, 32);
        if (ov > best1 || (ov == best1 && oi < bi1)) { best1 = ov; bi1 = oi; }
    }
    if (lane < 32) {
        smin[w][col]      = best0; sidx[w][col]      = bi0;   // rows 0..31
        smin[w][32 + col] = best1; sidx[w][32 + col] = bi1;   // rows 32..63
    }
    __syncthreads();

    // ---- wave 0: combine 4 code quarters per row, loss partial, publish indices
    if (w == 0) {
        float b = smin[0][lane]; int ix = sidx[0][lane];
        #pragma unroll
        for (int q = 1; q < 4; ++q) {
            const float bq = smin[q][lane]; const int iq = sidx[q][lane];
            if (bq > b) { b = bq; ix = iq; }    // strict: lower quarter wins ties
        }
        sfin[lane] = ix;
        float ls = -2.f * b;
        #pragma unroll
        for (int m = 32; m; m >>= 1) ls += __shfl_xor(ls, m);
        if (lane == 0)
            atomicAdd(loss_accum, ls + sxsq[0] + sxsq[1] + sxsq[2] + sxsq[3]);
    }
    __syncthreads();

    // ---- epilogue: gather fp32 codebook rows, dwordx4 stores along hw
    {
        const int q  = t & 15;     // rows 4q..4q+3
        const int dg = t >> 4;     // 0..15 -> d in [dg*16, dg*16+16)
        const int c0 = sfin[4 * q + 0], c1 = sfin[4 * q + 1];
        const int c2 = sfin[4 * q + 2], c3 = sfin[4 * q + 3];
        const float* r0 = cb + c0 * DIM;
        const float* r1 = cb + c1 * DIM;
        const float* r2 = cb + c2 * DIM;
        const float* r3 = cb + c3 * DIM;
        float* ob = out + (size_t)batch * (DIM * 1024) + hw0 + 4 * q;
        #pragma unroll 4
        for (int j = 0; j < 16; ++j) {
            const int d = dg * 16 + j;
            f32x4_t v; v.x = r0[d]; v.y = r1[d]; v.z = r2[d]; v.w = r3[d];
            *(f32x4_t*)(ob + (size_t)d * 1024) = v;
        }
    }
}

// ---- finalize loss ----
__global__ void vq_final(const float* __restrict__ loss_accum, float* __restrict__ out_loss) {
    *out_loss = 1.25f * (*loss_accum) / 16777216.f;
}

extern "C" void kernel_launch(void* const* d_in, const int* in_sizes, int n_in,
                              void* d_out, int out_size, void* d_ws, size_t ws_size,
                              hipStream_t stream) {
    const float* x  = (const float*)d_in[0];   // [64,256,32,32]
    const float* cb = (const float*)d_in[1];   // [1024,256]
    float* out = (float*)d_out;                // 16777216 + 1

    char* ws = (char*)d_ws;
    float* loss_accum = (float*)ws;                        // 4 B
    char*  cbsw       = ws + 1024;                         // 512 KB, A-frag order
    float* nh_ord     = (float*)(ws + 1024 + 512 * 1024);  // 4 KB

    hipMemsetAsync(loss_accum, 0, sizeof(float), stream);
    vq_prep<<<dim3(256), dim3(256), 0, stream>>>(cb, cbsw, nh_ord);
    vq_main<<<dim3(1024), dim3(256), 0, stream>>>(x, cb, (const bf16x8_t*)cbsw, nh_ord,
                                                  out, loss_accum);
    vq_final<<<dim3(1), dim3(1), 0, stream>>>(loss_accum, out + 16777216);
}

// Round 8
// 215.884 us; speedup vs baseline: 1.0003x; 1.0003x over previous
//
#include <hip/hip_runtime.h>
#include <hip/hip_bf16.h>
#include <stdint.h>

// VectorQuantizer on MI355X (gfx950) — round 8
// inputs: x [64,256,32,32] fp32 (NCHW), codebook [1024,256] fp32
// outputs: q_st [64,256,32,32] fp32 (codebook[argmin] scattered back), loss scalar
//
// Flipped GEMM D[m=code][n=hw] via mfma_f32_32x32x16_bf16; x staged once to
// LDS in B-frag order (R5). R7's 64x256 wave tile (2 n-tiles, dual acc) halved
// codebook L2 traffic but apre[16]+2acc spilled (WRITE 91 MB, 123 us).
// R8: A prefetch as two half-tile ping-pong arrays aA[8]/aB[8] (32+32 VGPR):
// next half-tile's 8 loads always issue before the current half's MFMAs,
// bounding outstanding loads at 8 with MFMA work in between — spill-free
// software pipeline. Peak regs ~130 < (256,3) cap 170.

#define DIM 256

typedef __attribute__((ext_vector_type(8)))  short bf16x8_t;   // MFMA A/B frag (4 VGPRs)
typedef __attribute__((ext_vector_type(4)))  float f32x4_t;
typedef __attribute__((ext_vector_type(16))) float f32x16_t;   // 32x32 C/D frag

__device__ __forceinline__ uint32_t f2bf(float f) {
    union { float f; uint32_t u; } v; v.f = f;
    uint32_t r = v.u + 0x7FFFu + ((v.u >> 16) & 1u);   // RNE
    return r >> 16;
}

// ---- prep: one wave per code. Emits (a) bf16 codebook in exact MFMA A-frag
// order: entry e=(mt*16+ks)*64+lane2 holds cb[mt*32+(lane2&31)][ks*16+(lane2>>5)*8+j],
// and (b) -0.5*||c||^2 in C/D-register order (nh_ord[mt*32 + half*16 + r]).
__global__ __launch_bounds__(256) void vq_prep(const float* __restrict__ cb,
                                               char* __restrict__ cbsw,
                                               float* __restrict__ nh_ord) {
    const int code = blockIdx.x * 4 + (threadIdx.x >> 6);
    const int l    = threadIdx.x & 63;               // holds d = 4l..4l+3
    const f32x4_t v = ((const f32x4_t*)(cb + code * DIM))[l];
    float sq = v.x * v.x + v.y * v.y + v.z * v.z + v.w * v.w;

    const int mt = code >> 5;
    const int ks = l >> 2;               // d/16
    const int hl = (l >> 1) & 1;         // (d%16)/8
    const uint32_t ebyte = (uint32_t)(((mt * 16 + ks) * 64 + (code & 31) + 32 * hl) * 16
                                      + (l & 1) * 8);
    uint2 o;
    o.x = f2bf(v.x) | (f2bf(v.y) << 16);
    o.y = f2bf(v.z) | (f2bf(v.w) << 16);
    *(uint2*)(cbsw + ebyte) = o;

    #pragma unroll
    for (int m = 32; m; m >>= 1) sq += __shfl_xor(sq, m);
    if (l == 0) {
        const int rw = code & 31;
        const int h4 = (rw >> 2) & 1;
        const int r  = (rw & 3) | ((rw >> 3) << 2);
        nh_ord[mt * 32 + h4 * 16 + r] = -0.5f * sq;
    }
}

// ---- main: 1024 blocks x 256 threads; block = 64 hw rows x all 1024 codes.
// LDS xt entry E=(ks*2+half)*64+row holds x[row][ks*16+half*8 .. +7] as 8 bf16.
// Wave w = code quarter (codes w*256..): both n-tiles (rows 0-31 / 32-63).
__global__ __launch_bounds__(256, 3) void vq_main(const float* __restrict__ x,
                                                  const float* __restrict__ cb,
                                                  const bf16x8_t* __restrict__ cbsw,
                                                  const float* __restrict__ nh_ord,
                                                  float* __restrict__ out,
                                                  float* __restrict__ loss_accum) {
    __shared__ uint32_t xt[16 * 2 * 64 * 4];   // 32 KB, B-frag order
    __shared__ float smin[4][64];
    __shared__ int   sidx[4][64];
    __shared__ float sxsq[4];
    __shared__ int   sfin[64];

    const int t     = threadIdx.x;
    const int w     = t >> 6;         // code quarter
    const int lane  = t & 63;
    const int n0    = blockIdx.x * 64;
    const int batch = n0 >> 10;
    const int hw0   = n0 & 1023;

    // ---- stage x -> LDS in fragment order (conflict-free b128 writes) + ||x||^2
    {
        const int col = t & 63;          // hw row within block
        const int oct = t >> 6;          // 0..3: d-octet selector
        const float* xp = x + (size_t)batch * (DIM * 1024) + hw0 + col;
        float sq = 0.f;
        #pragma unroll
        for (int i = 0; i < 8; ++i) {
            const int d0 = oct * 8 + i * 32;     // 8 consecutive d, one LDS entry
            float a[8];
            #pragma unroll
            for (int j = 0; j < 8; ++j) {
                a[j] = xp[(size_t)(d0 + j) * 1024];
                sq += a[j] * a[j];
            }
            uint4 pk;
            pk.x = f2bf(a[0]) | (f2bf(a[1]) << 16);
            pk.y = f2bf(a[2]) | (f2bf(a[3]) << 16);
            pk.z = f2bf(a[4]) | (f2bf(a[5]) << 16);
            pk.w = f2bf(a[6]) | (f2bf(a[7]) << 16);
            const int ks   = d0 >> 4;
            const int half = (d0 >> 3) & 1;
            *(uint4*)&xt[(ks * 512) + (half * 256) + col * 4] = pk;
        }
        #pragma unroll
        for (int m = 32; m; m >>= 1) sq += __shfl_xor(sq, m);
        if (lane == 0) sxsq[w] = sq;
    }
    __syncthreads();

    // ---- K-loop: wave's 256 codes (8 m-tiles) x both n-tiles.
    // A prefetch: half-tile ping-pong aA/aB (8 frags each) — next half's loads
    // issue before current half's MFMAs, keeping <=8 loads in flight.
    const int half = lane >> 5;
    const int col  = lane & 31;
    const uint32_t* xb0 = xt + half * 256 + col * 4;          // rows 0..31
    const uint32_t* xb1 = xb0 + 32 * 4;                        // rows 32..63

    float best0 = -3.0e38f, best1 = -3.0e38f;
    int   bi0 = 0, bi1 = 0;

    bf16x8_t aA[8], aB[8];
    {
        const bf16x8_t* ap0 = cbsw + (w * 8) * (16 * 64) + lane;
        #pragma unroll
        for (int k = 0; k < 8; ++k) aA[k] = ap0[k * 64];      // tile 0, ks 0..7
    }

    for (int i = 0; i < 8; ++i) {
        const int mt = w * 8 + i;
        const bf16x8_t* ap = cbsw + mt * (16 * 64) + lane;

        // issue second half of current tile (ks 8..15)
        #pragma unroll
        for (int k = 0; k < 8; ++k) aB[k] = ap[(8 + k) * 64];

        const f32x4_t* nhp = (const f32x4_t*)(nh_ord + mt * 32 + half * 16);
        const f32x4_t h0 = nhp[0], h1 = nhp[1], h2 = nhp[2], h3 = nhp[3];
        f32x16_t acc0, acc1;
        #pragma unroll
        for (int r = 0; r < 4; ++r) {
            acc0[r] = h0[r]; acc0[4 + r] = h1[r]; acc0[8 + r] = h2[r]; acc0[12 + r] = h3[r];
        }
        acc1 = acc0;

        // MFMA first half (consumes aA; aB loads draining behind)
        #pragma unroll
        for (int k = 0; k < 8; ++k) {
            const bf16x8_t b0 = *(const bf16x8_t*)(xb0 + k * 512);
            const bf16x8_t b1 = *(const bf16x8_t*)(xb1 + k * 512);
            acc0 = __builtin_amdgcn_mfma_f32_32x32x16_bf16(aA[k], b0, acc0, 0, 0, 0);
            acc1 = __builtin_amdgcn_mfma_f32_32x32x16_bf16(aA[k], b1, acc1, 0, 0, 0);
        }

        // issue first half of NEXT tile (refills aA while aB is consumed)
        if (i < 7) {
            const bf16x8_t* apn = ap + 16 * 64;
            #pragma unroll
            for (int k = 0; k < 8; ++k) aA[k] = apn[k * 64];
        }

        // MFMA second half (consumes aB)
        #pragma unroll
        for (int k = 0; k < 8; ++k) {
            const bf16x8_t b0 = *(const bf16x8_t*)(xb0 + (8 + k) * 512);
            const bf16x8_t b1 = *(const bf16x8_t*)(xb1 + (8 + k) * 512);
            acc0 = __builtin_amdgcn_mfma_f32_32x32x16_bf16(aB[k], b0, acc0, 0, 0, 0);
            acc1 = __builtin_amdgcn_mfma_f32_32x32x16_bf16(aB[k], b1, acc1, 0, 0, 0);
        }

        #pragma unroll
        for (int r = 0; r < 16; ++r) {
            const int code = mt * 32 + half * 4 + ((r & 3) + 8 * (r >> 2));
            if (acc0[r] > best0) { best0 = acc0[r]; bi0 = code; }
            if (acc1[r] > best1) { best1 = acc1[r]; bi1 = code; }
        }
    }

    // ---- combine the two k-half lanes (same hw row, disjoint code subsets)
    {
        float ov = __shfl_xor(best0, 32); int oi = __shfl_xor(bi0, 32);
        if (ov > best0 || (ov == best0 && oi < bi0)) { best0 = ov; bi0 = oi; }
        ov = __shfl_xor(best1, 32); oi = __shfl_xor(bi1, 32);
        if (ov > best1 || (ov == best1 && oi < bi1)) { best1 = ov; bi1 = oi; }
    }
    if (lane < 32) {
        smin[w][col]      = best0; sidx[w][col]      = bi0;   // rows 0..31
        smin[w][32 + col] = best1; sidx[w][32 + col] = bi1;   // rows 32..63
    }
    __syncthreads();

    // ---- wave 0: combine 4 code quarters per row, loss partial, publish indices
    if (w == 0) {
        float b = smin[0][lane]; int ix = sidx[0][lane];
        #pragma unroll
        for (int q = 1; q < 4; ++q) {
            const float bq = smin[q][lane]; const int iq = sidx[q][lane];
            if (bq > b) { b = bq; ix = iq; }    // strict: lower quarter wins ties
        }
        sfin[lane] = ix;
        float ls = -2.f * b;
        #pragma unroll
        for (int m = 32; m; m >>= 1) ls += __shfl_xor(ls, m);
        if (lane == 0)
            atomicAdd(loss_accum, ls + sxsq[0] + sxsq[1] + sxsq[2] + sxsq[3]);
    }
    __syncthreads();

    // ---- epilogue: gather fp32 codebook rows, dwordx4 stores along hw
    {
        const int q  = t & 15;     // rows 4q..4q+3
        const int dg = t >> 4;     // 0..15 -> d in [dg*16, dg*16+16)
        const int c0 = sfin[4 * q + 0], c1 = sfin[4 * q + 1];
        const int c2 = sfin[4 * q + 2], c3 = sfin[4 * q + 3];
        const float* r0 = cb + c0 * DIM;
        const float* r1 = cb + c1 * DIM;
        const float* r2 = cb + c2 * DIM;
        const float* r3 = cb + c3 * DIM;
        float* ob = out + (size_t)batch * (DIM * 1024) + hw0 + 4 * q;
        #pragma unroll 4
        for (int j = 0; j < 16; ++j) {
            const int d = dg * 16 + j;
            f32x4_t v; v.x = r0[d]; v.y = r1[d]; v.z = r2[d]; v.w = r3[d];
            *(f32x4_t*)(ob + (size_t)d * 1024) = v;
        }
    }
}

// ---- finalize loss ----
__global__ void vq_final(const float* __restrict__ loss_accum, float* __restrict__ out_loss) {
    *out_loss = 1.25f * (*loss_accum) / 16777216.f;
}

extern "C" void kernel_launch(void* const* d_in, const int* in_sizes, int n_in,
                              void* d_out, int out_size, void* d_ws, size_t ws_size,
                              hipStream_t stream) {
    const float* x  = (const float*)d_in[0];   // [64,256,32,32]
    const float* cb = (const float*)d_in[1];   // [1024,256]
    float* out = (float*)d_out;                // 16777216 + 1

    char* ws = (char*)d_ws;
    float* loss_accum = (float*)ws;                        // 4 B
    char*  cbsw       = ws + 1024;                         // 512 KB, A-frag order
    float* nh_ord     = (float*)(ws + 1024 + 512 * 1024);  // 4 KB

    hipMemsetAsync(loss_accum, 0, sizeof(float), stream);
    vq_prep<<<dim3(256), dim3(256), 0, stream>>>(cb, cbsw, nh_ord);
    vq_main<<<dim3(1024), dim3(256), 0, stream>>>(x, cb, (const bf16x8_t*)cbsw, nh_ord,
                                                  out, loss_accum);
    vq_final<<<dim3(1), dim3(1), 0, stream>>>(loss_accum, out + 16777216);
}